// Round 9
// baseline (529.184 us; speedup 1.0000x reference)
//
#include <hip/hip_runtime.h>
#include <hip/hip_bf16.h>

// Max-tree (component tree) per channel, 64x64x3. Outputs (float32):
// parents [3,4096] then altitudes [3,4096].
//
// ranks = stable descending sort position (distinct, 0 = highest f) act as
// altitudes; rank-image max-tree's uncompressed pixel-parent == reference's
// (validated r2-r8). Distinct ranks => UNIQUE tree => order-independent
// concurrent CAS-based ordered union over all 8064 edges (validated r5-r8).
//
// r9 (attacking LDS-issue throughput, the measured r8 bottleneck):
//  - state[2x] = parw, state[2x+1] = skipw; one ds_read_b64 per step
//  - loads gated by the per-slot active mask (no dead-slot LDS traffic)
//  - rank-sorted slots: thread t owns ranks {4t..4t+3} x 4 nbrs (edge kept
//    iff nbr rank < ry => each edge once, at its higher endpoint); wave w
//    owns rank band [256w,256w+256) -> short-walk waves exit early, freeing
//    the LDS pipe for the long top-band walks.
//
// Safety (r5-r8, schedule-agnostic):
//  - parw CAS is ABA-safe: non-root parent-rank strictly decreases, self
//    word never recurs. Climb on stale parent is safe: splices only INSERT
//    between x and parent => a once-read parent stays an ancestor forever.
//  - skipw[n] = (rank(t)<<12)|t, t ancestor-or-self of n; ranks strictly
//    ascend along root paths => jump safe iff rank(t) <= ry; deferred
//    halving (hint(px) := hint(x)) is ancestor-of-ancestor. Any racy hint
//    is still a valid ancestor (32-bit LDS stores are word-atomic).
// Canon closed form g[p] = climb-from-parent-while-f-equal (validated r2-r8).

#define N_PIX 4096
#define CH 3

// ---------------------------------------------------------------------------
// K1: stable descending rank: rank(p) = #{f[q]>f[p]} + #{f[q]==f[p], q<p}
// ---------------------------------------------------------------------------
__global__ __launch_bounds__(256) void ct_rank(const float* __restrict__ vw,
                                               int* __restrict__ rank_g) {
    __shared__ __align__(16) float vals[N_PIX];
    const int c   = blockIdx.x >> 4;
    const int seg = blockIdx.x & 15;
    const int tid = threadIdx.x;
    for (int i = tid; i < N_PIX; i += 256) vals[i] = vw[i * CH + c];
    __syncthreads();

    const int   p  = (seg << 8) + tid;
    const float vp = vals[p];
    int cnt = 0;
    const float4* v4 = reinterpret_cast<const float4*>(vals);
#pragma unroll 4
    for (int j4 = 0; j4 < N_PIX / 4; ++j4) {
        float4 q = v4[j4];
        int j = j4 << 2;
        cnt += (q.x > vp) || ((q.x == vp) && (j     < p));
        cnt += (q.y > vp) || ((q.y == vp) && (j + 1 < p));
        cnt += (q.z > vp) || ((q.z == vp) && (j + 2 < p));
        cnt += (q.w > vp) || ((q.w == vp) && (j + 3 < p));
    }
    rank_g[(c << 12) + p] = cnt;
}

// ---------------------------------------------------------------------------
// K2: concurrent ordered union (b64 state, gated loads, rank-sorted slots)
// + canon. One block per channel, 1024 threads, 16 slots per thread.
// ---------------------------------------------------------------------------
__global__ __launch_bounds__(1024) void ct_tree(const float* __restrict__ vw,
                                                const int* __restrict__ rank_g,
                                                float* __restrict__ out) {
    __shared__ __align__(16) unsigned state[2 * N_PIX];  // 32 KB (parw,skipw)
    __shared__ unsigned short rank16[N_PIX];             // 8 KB
    __shared__ unsigned short inv16[N_PIX];              // 8 KB
    __shared__ float          vals[N_PIX];               // 16 KB
    const int c   = blockIdx.x;
    const int tid = threadIdx.x;

    for (int p = tid; p < N_PIX; p += 1024) {
        const unsigned r = (unsigned)rank_g[(c << 12) + p];
        rank16[p]        = (unsigned short)r;
        inv16[r]         = (unsigned short)p;
        state[2 * p]     = (r << 12) | (unsigned)p;      // parw (self = root)
        state[2 * p + 1] = (r << 12) | (unsigned)p;      // skipw (self hint)
        vals[p]          = vw[p * CH + c];
    }
    __syncthreads();

    // ---- init 16 slots: ranks {4t..4t+3} x 4 neighbors ----
    int xA[16], pxA[16];
    unsigned ywA[16];
    unsigned act = 0;
#pragma unroll
    for (int k = 0; k < 16; ++k) {
        const int ry  = (tid << 2) + (k >> 2);
        const int y   = inv16[ry];
        const int row = y >> 6, col = y & 63;
        const int kk  = k & 3;
        int x; bool ok;
        if      (kk == 0) { x = y - 64; ok = row > 0;  }
        else if (kk == 1) { x = y + 64; ok = row < 63; }
        else if (kk == 2) { x = y - 1;  ok = col > 0;  }
        else              { x = y + 1;  ok = col < 63; }
        xA[k] = 0; pxA[k] = -1; ywA[k] = 0;
        if (ok && (int)rank16[x] < ry) {
            xA[k]  = x;
            ywA[k] = ((unsigned)ry << 12) | (unsigned)y;
            act   |= 1u << k;
        }
    }

    // ---- one macro-step for slot k on loaded 64-bit state ----
    auto step = [&](int k, unsigned long long lv) {
        const int      x  = xA[k];
        const unsigned yw = ywA[k];
        const unsigned ry = yw >> 12;
        const unsigned w  = (unsigned)lv;          // parw[x]
        const unsigned sk = (unsigned)(lv >> 32);  // skipw[x]
        if (pxA[k] >= 0) { state[2 * pxA[k] + 1] = sk; pxA[k] = -1; }  // halving
        const unsigned s = sk & 0xFFFu;
        if (s != (unsigned)x && (sk >> 12) <= ry) {            // jump via hint
            if (s == (yw & 0xFFFu)) act &= ~(1u << k);         // reached y
            else { pxA[k] = x; xA[k] = (int)s; }
            return;
        }
        const unsigned p  = w & 0xFFFu;
        const unsigned rp = w >> 12;
        if (p == (unsigned)x) {                                // root: attach y
            if (atomicCAS(&state[2 * x], w, yw) == w) {
                state[2 * x + 1] = yw;
                act &= ~(1u << k);
            }
        } else if (rp < ry) {                                  // climb + memo
            state[2 * x + 1] = w;
            xA[k] = (int)p;
        } else if (rp > ry) {                                  // splice y below p
            if (atomicCAS(&state[2 * x], w, yw) == w) {
                state[2 * x + 1] = yw;
                xA[k]  = (int)(yw & 0xFFFu);                   // continue from y
                ywA[k] = w;                                    // ...inserting p
            }
        } else act &= ~(1u << k);                              // rp==ry => p==y
    };

    // ---- interleaved macro-step loop (2 half-batches of 8 for VGPR budget) --
    while (act) {
        unsigned long long ld[8];
#pragma unroll
        for (int k = 0; k < 8; ++k)
            if (act & (1u << k))
                ld[k] = *((volatile unsigned long long*)&state[2 * xA[k]]);
#pragma unroll
        for (int k = 0; k < 8; ++k)
            if (act & (1u << k)) step(k, ld[k]);
#pragma unroll
        for (int k = 8; k < 16; ++k)
            if (act & (1u << k))
                ld[k - 8] = *((volatile unsigned long long*)&state[2 * xA[k]]);
#pragma unroll
        for (int k = 8; k < 16; ++k)
            if (act & (1u << k)) step(k, ld[k - 8]);
    }
    __syncthreads();

    // ---- canon (g[p] = climb-from-parent-while-f-equal) + output ----
    for (int p = tid; p < N_PIX; p += 1024) {
        int q = state[2 * p] & 0xFFF;
        const float fq = vals[q];
        for (;;) {
            const int qp = state[2 * q] & 0xFFF;
            if (qp == q) break;
            if (vals[qp] != fq) break;
            q = qp;
        }
        out[(c << 12) + p] = (float)q;
        out[CH * N_PIX + (c << 12) + p] = vals[p];
    }
}

extern "C" void kernel_launch(void* const* d_in, const int* in_sizes, int n_in,
                              void* d_out, int out_size, void* d_ws, size_t ws_size,
                              hipStream_t stream) {
    const float* vw = (const float*)d_in[0];
    float* out = (float*)d_out;

    int* rank_g = (int*)d_ws;   // 3*4096 ints

    ct_rank<<<48, 256, 0, stream>>>(vw, rank_g);
    ct_tree<<<CH, 1024, 0, stream>>>(vw, rank_g, out);
}

// Round 10
// 362.326 us; speedup vs baseline: 1.4605x; 1.4605x over previous
//
#include <hip/hip_runtime.h>
#include <hip/hip_bf16.h>

// Max-tree (component tree) per channel, 64x64x3. Outputs (float32):
// parents [3,4096] then altitudes [3,4096].
//
// ranks = stable descending sort position (distinct, 0 = highest f) act as
// altitudes; rank-image max-tree's uncompressed pixel-parent == reference's
// (validated r2-r9). Distinct ranks => UNIQUE tree => order-independent
// concurrent CAS-based ordered union over all 8064 edges (validated r5-r9).
//
// r10 = r8's SCATTERED edge map (uniform tail across 1024 threads; r9's
// rank-banded map concentrated all long walks in one wave -> regression)
// + r9's micro-opts (fused b64 state -> one ds_read_b64 per step; loads
// gated by the active mask -> no dead-slot LDS traffic).
//
// Safety (r5-r9, schedule-agnostic):
//  - state[2x]=parw, state[2x+1]=skipw. parw CAS is ABA-safe: non-root
//    parent-rank strictly decreases, self word never recurs. Climb on a
//    stale parent is safe: splices only INSERT between x and its parent,
//    so a once-read parent remains an ancestor forever.
//  - skipw[n] = (rank(t)<<12)|t, t ancestor-or-self of n; ranks strictly
//    ascend along root paths => jump safe iff rank(t) <= ry; deferred
//    halving (hint(px) := hint(x)) is ancestor-of-ancestor. Racy hints are
//    still valid ancestors (32-bit LDS stores are word-atomic).
// Canon closed form g[p] = climb-from-parent-while-f-equal (validated r2-r9).

#define N_PIX 4096
#define CH 3

// ---------------------------------------------------------------------------
// K1: stable descending rank: rank(p) = #{f[q]>f[p]} + #{f[q]==f[p], q<p}
// ---------------------------------------------------------------------------
__global__ __launch_bounds__(256) void ct_rank(const float* __restrict__ vw,
                                               int* __restrict__ rank_g) {
    __shared__ __align__(16) float vals[N_PIX];
    const int c   = blockIdx.x >> 4;
    const int seg = blockIdx.x & 15;
    const int tid = threadIdx.x;
    for (int i = tid; i < N_PIX; i += 256) vals[i] = vw[i * CH + c];
    __syncthreads();

    const int   p  = (seg << 8) + tid;
    const float vp = vals[p];
    int cnt = 0;
    const float4* v4 = reinterpret_cast<const float4*>(vals);
#pragma unroll 4
    for (int j4 = 0; j4 < N_PIX / 4; ++j4) {
        float4 q = v4[j4];
        int j = j4 << 2;
        cnt += (q.x > vp) || ((q.x == vp) && (j     < p));
        cnt += (q.y > vp) || ((q.y == vp) && (j + 1 < p));
        cnt += (q.z > vp) || ((q.z == vp) && (j + 2 < p));
        cnt += (q.w > vp) || ((q.w == vp) && (j + 3 < p));
    }
    rank_g[(c << 12) + p] = cnt;
}

// ---------------------------------------------------------------------------
// K2: concurrent ordered union (scattered edges, gated b64 loads) + canon.
// One block per channel, 1024 threads, 8 edge slots per thread.
// ---------------------------------------------------------------------------
__global__ __launch_bounds__(1024) void ct_tree(const float* __restrict__ vw,
                                                const int* __restrict__ rank_g,
                                                float* __restrict__ out) {
    __shared__ __align__(16) unsigned state[2 * N_PIX];  // 32 KB (parw,skipw)
    __shared__ unsigned short rank16[N_PIX];             // 8 KB
    __shared__ float          vals[N_PIX];               // 16 KB
    const int c   = blockIdx.x;
    const int tid = threadIdx.x;

    for (int p = tid; p < N_PIX; p += 1024) {
        const unsigned r = (unsigned)rank_g[(c << 12) + p];
        rank16[p]        = (unsigned short)r;
        state[2 * p]     = (r << 12) | (unsigned)p;      // parw (self = root)
        state[2 * p + 1] = (r << 12) | (unsigned)p;      // skipw (self hint)
        vals[p]          = vw[p * CH + c];
    }
    __syncthreads();

    // ---- init 8 walk slots (scattered: e = k*1024 + tid) ----
    int xA[8], pxA[8];
    unsigned ywA[8];
    unsigned act = 0;
#pragma unroll
    for (int k = 0; k < 8; ++k) {
        xA[k] = 0; pxA[k] = -1; ywA[k] = 0;
        const int e = (k << 10) + tid;
        if (e < 8064) {
            int x, y;
            if (e < 4032) { const int row = e / 63; x = row * 64 + (e - row * 63); y = x + 1; }
            else          { const int e2 = e - 4032; x = ((e2 >> 6) << 6) + (e2 & 63); y = x + 64; }
            unsigned rx = rank16[x], ry = rank16[y];
            if (rx > ry) { int t = x; x = y; y = t; unsigned tr = rx; rx = ry; ry = tr; }
            xA[k]  = x;
            ywA[k] = (ry << 12) | (unsigned)y;
            act   |= 1u << k;
        }
    }

    // ---- one macro-step for slot k on loaded 64-bit state ----
    auto step = [&](int k, unsigned long long lv) {
        const int      x  = xA[k];
        const unsigned yw = ywA[k];
        const unsigned ry = yw >> 12;
        const unsigned w  = (unsigned)lv;          // parw[x]
        const unsigned sk = (unsigned)(lv >> 32);  // skipw[x]
        if (pxA[k] >= 0) { state[2 * pxA[k] + 1] = sk; pxA[k] = -1; }  // halving
        const unsigned s = sk & 0xFFFu;
        if (s != (unsigned)x && (sk >> 12) <= ry) {            // jump via hint
            if (s == (yw & 0xFFFu)) act &= ~(1u << k);         // reached y
            else { pxA[k] = x; xA[k] = (int)s; }
            return;
        }
        const unsigned p  = w & 0xFFFu;
        const unsigned rp = w >> 12;
        if (p == (unsigned)x) {                                // root: attach y
            if (atomicCAS(&state[2 * x], w, yw) == w) {
                state[2 * x + 1] = yw;
                act &= ~(1u << k);
            }
        } else if (rp < ry) {                                  // climb + memo
            state[2 * x + 1] = w;
            xA[k] = (int)p;
        } else if (rp > ry) {                                  // splice y below p
            if (atomicCAS(&state[2 * x], w, yw) == w) {
                state[2 * x + 1] = yw;
                xA[k]  = (int)(yw & 0xFFFu);                   // continue from y
                ywA[k] = w;                                    // ...inserting p
            }
        } else act &= ~(1u << k);                              // rp==ry => p==y
    };

    // ---- interleaved macro-step loop: gated batched loads, then steps ----
    while (act) {
        unsigned long long ld[8];
#pragma unroll
        for (int k = 0; k < 8; ++k)
            if (act & (1u << k))
                ld[k] = *((volatile unsigned long long*)&state[2 * xA[k]]);
#pragma unroll
        for (int k = 0; k < 8; ++k)
            if (act & (1u << k)) step(k, ld[k]);
    }
    __syncthreads();

    // ---- canon (g[p] = climb-from-parent-while-f-equal) + output ----
    for (int p = tid; p < N_PIX; p += 1024) {
        int q = state[2 * p] & 0xFFF;
        const float fq = vals[q];
        for (;;) {
            const int qp = state[2 * q] & 0xFFF;
            if (qp == q) break;
            if (vals[qp] != fq) break;
            q = qp;
        }
        out[(c << 12) + p] = (float)q;
        out[CH * N_PIX + (c << 12) + p] = vals[p];
    }
}

extern "C" void kernel_launch(void* const* d_in, const int* in_sizes, int n_in,
                              void* d_out, int out_size, void* d_ws, size_t ws_size,
                              hipStream_t stream) {
    const float* vw = (const float*)d_in[0];
    float* out = (float*)d_out;

    int* rank_g = (int*)d_ws;   // 3*4096 ints

    ct_rank<<<48, 256, 0, stream>>>(vw, rank_g);
    ct_tree<<<CH, 1024, 0, stream>>>(vw, rank_g, out);
}